// Round 6
// baseline (7947.731 us; speedup 1.0000x reference)
//
#include <hip/hip_runtime.h>
#include <stdint.h>

// EncDecAD: encoder LSTM (256) -> Linear -> self-feeding decoder LSTM (256).
// R9 = R3 dataflow/sync EXACTLY, retiled: group = 4 blocks x 64 cols (was 16
// blocks x 16 cols). 64 blocks total, 16 groups x 32 batch rows. Each wave
// owns 16 cols (4 MFMA n-tiles); weights VGPR-resident (~128 regs; 1
// wave/SIMD -> 512-reg budget, no occupancy change). Chip-wide coherent
// h-reads per step: 16 MB -> 4 MB with ZERO new barriers/LDS on the h-path
// (the confound that sank R5/R6/R8). Poll gather 64 -> 16 sectors. Sync
// protocol, slot ping-pong, numerics: bitwise-identical to R3.

#define H_ 256
#define B_ 512
#define T_ 256

typedef short short8 __attribute__((ext_vector_type(8)));
typedef float f32x4 __attribute__((ext_vector_type(4)));

__device__ __forceinline__ short f2bf(float f) {
  union { float f; uint32_t u; } v; v.f = f;
  uint32_t r = (v.u + 0x7FFFu + ((v.u >> 16) & 1u)) >> 16;  // RNE
  return (short)(uint16_t)r;
}

__device__ __forceinline__ short8 load8f_bf(const float* __restrict__ p) {
  const float4 a = *(const float4*)p;
  const float4 b = *(const float4*)(p + 4);
  short8 r;
  r[0]=f2bf(a.x); r[1]=f2bf(a.y); r[2]=f2bf(a.z); r[3]=f2bf(a.w);
  r[4]=f2bf(b.x); r[5]=f2bf(b.y); r[6]=f2bf(b.z); r[7]=f2bf(b.w);
  return r;
}

__device__ __forceinline__ short8 load8f_bf_sum(const float* __restrict__ p,
                                                const float* __restrict__ q) {
  const float4 a = *(const float4*)p, b = *(const float4*)(p + 4);
  const float4 c = *(const float4*)q, d = *(const float4*)(q + 4);
  short8 r;
  r[0]=f2bf(a.x+c.x); r[1]=f2bf(a.y+c.y); r[2]=f2bf(a.z+c.z); r[3]=f2bf(a.w+c.w);
  r[4]=f2bf(b.x+d.x); r[5]=f2bf(b.y+d.y); r[6]=f2bf(b.z+d.z); r[7]=f2bf(b.w+d.w);
  return r;
}

__device__ __forceinline__ short8 coh_load16(const uint16_t* p) {
  union { uint64_t u[2]; short8 v; } r;
  const uint64_t* q = (const uint64_t*)p;
  r.u[0] = __hip_atomic_load(q,     __ATOMIC_RELAXED, __HIP_MEMORY_SCOPE_AGENT);
  r.u[1] = __hip_atomic_load(q + 1, __ATOMIC_RELAXED, __HIP_MEMORY_SCOPE_AGENT);
  return r.v;
}

__device__ __forceinline__ float sigm(float x)  { return 1.0f / (1.0f + __expf(-x)); }
__device__ __forceinline__ float tanh_(float x) { return 1.0f - 2.0f / (1.0f + __expf(2.0f * x)); }

__global__ __launch_bounds__(256, 1) void encdec_kernel(
    const float* __restrict__ x,
    const float* __restrict__ Wih1, const float* __restrict__ Whh1,
    const float* __restrict__ bih1, const float* __restrict__ bhh1,
    const float* __restrict__ W1,   const float* __restrict__ b1,
    const float* __restrict__ Wih2, const float* __restrict__ Whh2,
    const float* __restrict__ bih2, const float* __restrict__ bhh2,
    float* __restrict__ out,
    uint32_t* __restrict__ bar,
    uint16_t* __restrict__ hbuf)
{
  __shared__ __align__(16) uint16_t hsh[32][64];  // block's h tile (b_loc x 64 cols), bf16
  __shared__ __align__(16) float    osh[32][64];  // block's out tile, fp32 (decoder)

  const int tid = threadIdx.x;
  const int l   = tid & 63;
  const int w   = tid >> 6;
  const int blk = blockIdx.x;                      // 0..63
  const int gid = (blk & 7) | ((blk >> 5) << 3);   // 0..15; members share blk%8 (XCD locality)
  const int mid = (blk >> 3) & 3;                  // 0..3 member within group
  const int bg  = gid * 32;
  const int cbase = mid * 64 + w * 16;             // wave's 16-col slice base

  const int nl   = l & 15;
  const int kc   = l >> 4;
  const int gate = nl >> 2;
  const int cm   = nl & 3;

  // flags: one 32B sector per wave-flag; 16 wave-flags per group
  uint32_t* flags = bar + (size_t)gid * 512;
  const int myflag = (mid * 4 + w) * 8;

  uint16_t* slot0 = hbuf;
  uint16_t* slot1 = hbuf + (size_t)B_ * H_;
  uint16_t* slot2 = hbuf + (size_t)2 * B_ * H_;

  auto arrive = [&](int target) {
    asm volatile("s_waitcnt vmcnt(0)" ::: "memory");   // my coherent stores are visible
    if (l == 0)
      __hip_atomic_store(&flags[myflag], (uint32_t)target,
                         __ATOMIC_RELAXED, __HIP_MEMORY_SCOPE_AGENT);
  };
  auto poll = [&](int target) {
    int g = 0;
    while ((int)__hip_atomic_load(&flags[(l & 15) * 8], __ATOMIC_RELAXED,
                                  __HIP_MEMORY_SCOPE_AGENT) < target) {
      __builtin_amdgcn_s_sleep(1);
      if (++g > 2000000) break;  // fail-wrong, not hang
    }
    asm volatile("" ::: "memory");
  };
  auto ldsbar = [&]() {
    asm volatile("s_waitcnt lgkmcnt(0)\n\ts_barrier" ::: "memory");
  };

  // weight row for n-tile nt: rows gate*H + (cbase + nt*4 + cm)
  auto grow = [&](int nt) { return gate * H_ + cbase + nt * 4 + cm; };

  // ---- encoder weight fragments (B-operand: lane nl = (gate,cm)) ----
  short8 fwa[4][8], fwb[4][8];
  float bias1v[4];
#pragma unroll
  for (int nt = 0; nt < 4; ++nt) {
    const size_t ro = (size_t)grow(nt) * H_;
#pragma unroll
    for (int kt = 0; kt < 8; ++kt) {
      fwa[nt][kt] = load8f_bf(Wih1 + ro + kt * 32 + kc * 8);
      fwb[nt][kt] = load8f_bf(Whh1 + ro + kt * 32 + kc * 8);
    }
    bias1v[nt] = bih1[grow(nt)] + bhh1[grow(nt)];
  }

  float cst[2][4][4];
#pragma unroll
  for (int mt = 0; mt < 2; ++mt)
#pragma unroll
    for (int nt = 0; nt < 4; ++nt)
#pragma unroll
      for (int r = 0; r < 4; ++r) cst[mt][nt][r] = 0.0f;

  // gate math + LDS gather-write (hn only for r==gate; (mt,nt,kc,gate,cm) unique)
  auto epi = [&](const f32x4 (&acc)[2][4], const float* biasv, bool wout) {
    const int rb = (l & 48) | cm;
#pragma unroll
    for (int mt = 0; mt < 2; ++mt)
#pragma unroll
      for (int nt = 0; nt < 4; ++nt) {
        float hn = 0.f;
#pragma unroll
        for (int r = 0; r < 4; ++r) {
          float z = acc[mt][nt][r] + biasv[nt];
          float a = (gate == 2) ? tanh_(z) : sigm(z);
          float ti = __shfl(a, rb,      64);
          float tf = __shfl(a, rb | 4,  64);
          float tg = __shfl(a, rb | 8,  64);
          float to = __shfl(a, rb | 12, 64);
          float cn = tf * cst[mt][nt][r] + ti * tg;
          cst[mt][nt][r] = cn;
          if (r == gate) hn = to * tanh_(cn);
        }
        hsh[mt * 16 + kc * 4 + gate][w * 16 + nt * 4 + cm] = (uint16_t)f2bf(hn);
        if (wout) osh[mt * 16 + kc * 4 + gate][w * 16 + nt * 4 + cm] = hn;
      }
  };

  const int gb = tid >> 3;          // gather: b_loc 0..31
  const int gc = tid & 7;           // 16B chunk within the block's 128B row-chunk

  // publish block's h tile (2x u64 coherent stores per thread, 4KB/block)
  auto pub_h = [&](uint16_t* hw) {
    uint64_t v0 = *(const uint64_t*)&hsh[gb][gc * 8];
    uint64_t v1 = *(const uint64_t*)&hsh[gb][gc * 8 + 4];
    uint64_t* d = (uint64_t*)&hw[(size_t)(bg + gb) * H_ + mid * 64 + gc * 8];
    __hip_atomic_store(d,     v0, __ATOMIC_RELAXED, __HIP_MEMORY_SCOPE_AGENT);
    __hip_atomic_store(d + 1, v1, __ATOMIC_RELAXED, __HIP_MEMORY_SCOPE_AGENT);
  };
  // publish block's out tile (4x u64 plain stores per thread, 8KB/block)
  auto pub_out = [&](int j) {
    float* d = &out[((size_t)(bg + gb) * T_ + j) * H_ + mid * 64 + gc * 8];
    const float* s = &osh[gb][gc * 8];
    *(uint64_t*)(d + 0) = *(const uint64_t*)(s + 0);
    *(uint64_t*)(d + 2) = *(const uint64_t*)(s + 2);
    *(uint64_t*)(d + 4) = *(const uint64_t*)(s + 4);
    *(uint64_t*)(d + 6) = *(const uint64_t*)(s + 6);
  };

  // x-part MFMAs for step t (independent of h) -> runs post-flag, pre-poll
  f32x4 accN[2][4];
  auto xmfma = [&](int t) {
#pragma unroll
    for (int mt = 0; mt < 2; ++mt) {
      const float* xr = x + ((size_t)(bg + mt * 16 + nl) * T_ + t) * H_ + kc * 8;
#pragma unroll
      for (int nt = 0; nt < 4; ++nt) accN[mt][nt] = (f32x4){0.f, 0.f, 0.f, 0.f};
#pragma unroll
      for (int kt = 0; kt < 8; ++kt) {
        short8 af = load8f_bf(xr + kt * 32);
#pragma unroll
        for (int nt = 0; nt < 4; ++nt)
          accN[mt][nt] = __builtin_amdgcn_mfma_f32_16x16x32_bf16(af, fwa[nt][kt], accN[mt][nt], 0, 0, 0);
      }
    }
  };
  xmfma(0);

  // ---------------- encoder ----------------
  for (int t = 0; t < T_; ++t) {
    f32x4 acc[2][4];
#pragma unroll
    for (int mt = 0; mt < 2; ++mt)
#pragma unroll
      for (int nt = 0; nt < 4; ++nt) acc[mt][nt] = accN[mt][nt];
    if (t > 0) {
      poll(t);
      const uint16_t* hs = (t & 1) ? slot1 : slot0;
#pragma unroll
      for (int mt = 0; mt < 2; ++mt) {
        const uint16_t* hr = hs + (size_t)(bg + mt * 16 + nl) * H_ + kc * 8;
#pragma unroll
        for (int kt = 0; kt < 8; ++kt) {
          short8 hA = coh_load16(hr + kt * 32);
#pragma unroll
          for (int nt = 0; nt < 4; ++nt)
            acc[mt][nt] = __builtin_amdgcn_mfma_f32_16x16x32_bf16(hA, fwb[nt][kt], acc[mt][nt], 0, 0, 0);
        }
      }
    }
    epi(acc, bias1v, false);
    ldsbar();
    pub_h(((t + 1) & 1) ? slot1 : slot0);
    arrive(t + 1);
    if (t + 1 < T_) xmfma(t + 1);   // overlapped with peers' arrival
  }

  // ---------------- x_end = h1 @ W1.T + b1  (h1 in slot0) ----------------
  poll(T_);
  {
    const int xcol = cbase + nl;    // each wave owns a distinct 16-col slice
    short8 fw1[8];
#pragma unroll
    for (int kt = 0; kt < 8; ++kt)
      fw1[kt] = load8f_bf(W1 + (size_t)xcol * H_ + kt * 32 + kc * 8);
    f32x4 acc[2] = { {0.f,0.f,0.f,0.f}, {0.f,0.f,0.f,0.f} };
#pragma unroll
    for (int mt = 0; mt < 2; ++mt) {
      const uint16_t* hr = slot0 + (size_t)(bg + mt * 16 + nl) * H_ + kc * 8;
#pragma unroll
      for (int kt = 0; kt < 8; ++kt) {
        short8 af = coh_load16(hr + kt * 32);
        acc[mt] = __builtin_amdgcn_mfma_f32_16x16x32_bf16(af, fw1[kt], acc[mt], 0, 0, 0);
      }
    }
    float bb = b1[xcol];
#pragma unroll
    for (int mt = 0; mt < 2; ++mt)
#pragma unroll
      for (int r = 0; r < 4; ++r) {
        int b = bg + mt * 16 + kc * 4 + r;
        __hip_atomic_store(&slot2[(size_t)b * H_ + xcol], (uint16_t)f2bf(acc[mt][r] + bb),
                           __ATOMIC_RELAXED, __HIP_MEMORY_SCOPE_AGENT);
      }
  }
  arrive(T_ + 1);

  // decoder t=0 weights in the window (fwa2/fwb2 only; fws loaded after t0)
  short8 fwa2[4][8], fwb2[4][8];
  float bias2v[4];
#pragma unroll
  for (int nt = 0; nt < 4; ++nt) {
    const size_t ro = (size_t)(gate * H_ + cbase + nt * 4 + cm) * H_;
#pragma unroll
    for (int kt = 0; kt < 8; ++kt) {
      fwa2[nt][kt] = load8f_bf(Wih2 + ro + kt * 32 + kc * 8);
      fwb2[nt][kt] = load8f_bf(Whh2 + ro + kt * 32 + kc * 8);
    }
    const int g2 = gate * H_ + cbase + nt * 4 + cm;
    bias2v[nt] = bih2[g2] + bhh2[g2];
  }
  poll(T_ + 1);

  // ---------------- decoder t=0 (x_end w/ fwa2, h1 w/ fwb2) ----------------
  {
    f32x4 acc[2][4];
#pragma unroll
    for (int mt = 0; mt < 2; ++mt)
#pragma unroll
      for (int nt = 0; nt < 4; ++nt) acc[mt][nt] = (f32x4){0.f, 0.f, 0.f, 0.f};
#pragma unroll
    for (int mt = 0; mt < 2; ++mt) {
      const size_t ro = (size_t)(bg + mt * 16 + nl) * H_ + kc * 8;
#pragma unroll
      for (int kt = 0; kt < 8; ++kt) {
        short8 hA = coh_load16(slot2 + ro + kt * 32);
        short8 hB = coh_load16(slot0 + ro + kt * 32);
#pragma unroll
        for (int nt = 0; nt < 4; ++nt) {
          acc[mt][nt] = __builtin_amdgcn_mfma_f32_16x16x32_bf16(hA, fwa2[nt][kt], acc[mt][nt], 0, 0, 0);
          acc[mt][nt] = __builtin_amdgcn_mfma_f32_16x16x32_bf16(hB, fwb2[nt][kt], acc[mt][nt], 0, 0, 0);
        }
      }
    }
    epi(acc, bias2v, true);
    ldsbar();
    pub_h(slot1);
    arrive(T_ + 2);
    pub_out(T_ - 2);
  }

  // merged decoder weights (x_t == h_{t-1}) in the flight window
  short8 fws[4][8];
#pragma unroll
  for (int nt = 0; nt < 4; ++nt) {
    const size_t ro = (size_t)(gate * H_ + cbase + nt * 4 + cm) * H_;
#pragma unroll
    for (int kt = 0; kt < 8; ++kt)
      fws[nt][kt] = load8f_bf_sum(Wih2 + ro + kt * 32 + kc * 8,
                                  Whh2 + ro + kt * 32 + kc * 8);
  }

  // ---------------- decoder t>=1 (merged weights) ----------------
  for (int t = 1; t < T_; ++t) {
    poll(T_ + 1 + t);
    const uint16_t* hs = (t & 1) ? slot1 : slot0;
    f32x4 acc[2][4];
#pragma unroll
    for (int mt = 0; mt < 2; ++mt)
#pragma unroll
      for (int nt = 0; nt < 4; ++nt) acc[mt][nt] = (f32x4){0.f, 0.f, 0.f, 0.f};
#pragma unroll
    for (int mt = 0; mt < 2; ++mt) {
      const uint16_t* hr = hs + (size_t)(bg + mt * 16 + nl) * H_ + kc * 8;
#pragma unroll
      for (int kt = 0; kt < 8; ++kt) {
        short8 hA = coh_load16(hr + kt * 32);
#pragma unroll
        for (int nt = 0; nt < 4; ++nt)
          acc[mt][nt] = __builtin_amdgcn_mfma_f32_16x16x32_bf16(hA, fws[nt][kt], acc[mt][nt], 0, 0, 0);
      }
    }
    epi(acc, bias2v, true);
    ldsbar();
    const int j = (t == T_ - 1) ? (T_ - 1) : (T_ - 2 - t);
    if (t + 1 < T_) {
      pub_h(((t + 1) & 1) ? slot1 : slot0);
      arrive(T_ + 2 + t);
    }
    pub_out(j);
  }
}

extern "C" void kernel_launch(void* const* d_in, const int* in_sizes, int n_in,
                              void* d_out, int out_size, void* d_ws, size_t ws_size,
                              hipStream_t stream) {
  const float* x    = (const float*)d_in[0];
  const float* Wih1 = (const float*)d_in[1];
  const float* Whh1 = (const float*)d_in[2];
  const float* bih1 = (const float*)d_in[3];
  const float* bhh1 = (const float*)d_in[4];
  const float* W1   = (const float*)d_in[5];
  const float* b1   = (const float*)d_in[6];
  const float* Wih2 = (const float*)d_in[7];
  const float* Whh2 = (const float*)d_in[8];
  const float* bih2 = (const float*)d_in[9];
  const float* bhh2 = (const float*)d_in[10];
  float* out = (float*)d_out;

  uint32_t* bar  = (uint32_t*)d_ws;                   // 16 groups x 2 KiB flag regions
  uint16_t* hbuf = (uint16_t*)((char*)d_ws + 32768);  // 3 bf16 (B,H) slots

  hipLaunchKernelGGL(encdec_kernel, dim3(64), dim3(256), 0, stream,
                     x, Wih1, Whh1, bih1, bhh1, W1, b1, Wih2, Whh2, bih2, bhh2,
                     out, bar, hbuf);
}